// Round 2
// baseline (374.844 us; speedup 1.0000x reference)
//
#include <hip/hip_runtime.h>

// x: (B=8, L=8192, D=512) fp32.  out: (B, 2048, D) fp32.
// out[b,i,d] = (sum_{l<=4(i+1)-1} x[b,l,d]) / (4(i+1))
//
// Fused single-pass chunked scan, R7: R6 was latency-bound (1 TB/s, 12.7%
// peak; VGPR_Count=68 proved the 16 vf4 checkpoints got parked in AGPRs and
// the load pipeline collapsed; 8 waves/CU gave no TLP to hide it).
// Fix: NC 128->256 (CL=32), so:
//   * checkpoints = 8 vf4 = 32 VGPR  -> stay in arch VGPRs, no AGPR traffic
//   * grid = 1024 blocks = 16 waves/CU (2x TLP), co-residency GUARANTEED by
//     __launch_bounds__(256,4) (VGPR cap 128 -> 4 blocks/CU on 256 CUs)
//   * 16-deep NT load batches (64 VGPR in flight, ~112 total) -> >=16 KB
//     in flight per wave; BW becomes latency-insensitive (fixes the
//     cold-L3 timed-loop case where poison fill evicts x).
// Phase B prefix doubles to avg 128 iters; 8 independent accumulators keep
// the dependent-latency tail ~3 us; aggregate 537 MB of L2 reads ~ 16 us.

#define BB   8
#define LL   8192
#define DD4  128            // D / 4 (float4 granularity)
#define NC   256            // chunks along L
#define CL   (LL / NC)      // 32 rows per chunk
#define OPC  (CL / 4)       // 8 outputs per chunk per column
#define OL   (LL / 4)       // 2048 output rows
#define NBLK 1024           // grid size; co-resident by __launch_bounds__(256,4)
#define SUMS_BYTES ((size_t)BB * NC * DD4 * 16)   // 4 MiB of chunk totals

typedef float vf4 __attribute__((ext_vector_type(4)));

__global__ __launch_bounds__(256, 4) void ds_fused(const vf4* __restrict__ x,
                                                   vf4* __restrict__ sums,
                                                   unsigned int* __restrict__ cnt,
                                                   vf4* __restrict__ out) {
    const int tid = blockIdx.x * blockDim.x + threadIdx.x;
    const int d4 = tid & (DD4 - 1);
    const int c  = (tid >> 7) & (NC - 1);
    const int b  = tid >> 15;

    const vf4* p = x + (((size_t)b * LL + c * CL) * DD4 + d4);

    // ---- phase A: stream chunk, checkpoints -> registers ----
    vf4 v[OPC];                       // 8 x vf4 = 32 VGPR, statically indexed
    vf4 s = (vf4)0.f;
    #pragma unroll
    for (int j = 0; j < CL; j += 16) {
        // 16 independent NT loads in flight before any use (x never re-read)
        vf4 v0  = __builtin_nontemporal_load(&p[(j +  0) * DD4]);
        vf4 v1  = __builtin_nontemporal_load(&p[(j +  1) * DD4]);
        vf4 v2  = __builtin_nontemporal_load(&p[(j +  2) * DD4]);
        vf4 v3  = __builtin_nontemporal_load(&p[(j +  3) * DD4]);
        vf4 v4  = __builtin_nontemporal_load(&p[(j +  4) * DD4]);
        vf4 v5  = __builtin_nontemporal_load(&p[(j +  5) * DD4]);
        vf4 v6  = __builtin_nontemporal_load(&p[(j +  6) * DD4]);
        vf4 v7  = __builtin_nontemporal_load(&p[(j +  7) * DD4]);
        vf4 v8  = __builtin_nontemporal_load(&p[(j +  8) * DD4]);
        vf4 v9  = __builtin_nontemporal_load(&p[(j +  9) * DD4]);
        vf4 v10 = __builtin_nontemporal_load(&p[(j + 10) * DD4]);
        vf4 v11 = __builtin_nontemporal_load(&p[(j + 11) * DD4]);
        vf4 v12 = __builtin_nontemporal_load(&p[(j + 12) * DD4]);
        vf4 v13 = __builtin_nontemporal_load(&p[(j + 13) * DD4]);
        vf4 v14 = __builtin_nontemporal_load(&p[(j + 14) * DD4]);
        vf4 v15 = __builtin_nontemporal_load(&p[(j + 15) * DD4]);
        s += v0 + v1 + v2 + v3;
        v[(j >> 2) + 0] = s;
        s += v4 + v5 + v6 + v7;
        v[(j >> 2) + 1] = s;
        s += v8 + v9 + v10 + v11;
        v[(j >> 2) + 2] = s;
        s += v12 + v13 + v14 + v15;
        v[(j >> 2) + 3] = s;
    }
    sums[(b * NC + c) * DD4 + d4] = s;      // chunk total (cached store)

    // ---- manual grid barrier ----
    __syncthreads();                        // all waves: vmcnt(0) -> stores in L2
    if (threadIdx.x == 0) {
        __threadfence();                    // agent release
        __hip_atomic_fetch_add(cnt, 1u, __ATOMIC_RELEASE, __HIP_MEMORY_SCOPE_AGENT);
        while (__hip_atomic_load(cnt, __ATOMIC_RELAXED, __HIP_MEMORY_SCOPE_AGENT) < NBLK)
            __builtin_amdgcn_s_sleep(8);
        __threadfence();                    // agent acquire
    }
    __syncthreads();

    // ---- phase B: exclusive prefix over preceding chunk totals ----
    // 8 independent accumulators; sums is 4 MiB, L2-resident after refetch.
    vf4 r0 = (vf4)0.f, r1 = (vf4)0.f, r2 = (vf4)0.f, r3 = (vf4)0.f;
    vf4 r4 = (vf4)0.f, r5 = (vf4)0.f, r6 = (vf4)0.f, r7 = (vf4)0.f;
    const vf4* sp = sums + b * NC * DD4 + d4;
    int q = 0;
    for (; q + 8 <= c; q += 8) {
        r0 += sp[(q + 0) * DD4];
        r1 += sp[(q + 1) * DD4];
        r2 += sp[(q + 2) * DD4];
        r3 += sp[(q + 3) * DD4];
        r4 += sp[(q + 4) * DD4];
        r5 += sp[(q + 5) * DD4];
        r6 += sp[(q + 6) * DD4];
        r7 += sp[(q + 7) * DD4];
    }
    for (; q < c; ++q) r0 += sp[q * DD4];
    const vf4 r = ((r0 + r1) + (r2 + r3)) + ((r4 + r5) + (r6 + r7));

    // ---- phase C: scale registers, single final write ----
    vf4* o = out + (((size_t)b * OL + c * OPC) * DD4 + d4);
    const int base = c * CL;
    #pragma unroll
    for (int k = 0; k < OPC; ++k) {
        const float inv = 1.0f / (float)(base + 4 * k + 4);
        __builtin_nontemporal_store((v[k] + r) * inv, &o[(size_t)k * DD4]);
    }
}

extern "C" void kernel_launch(void* const* d_in, const int* in_sizes, int n_in,
                              void* d_out, int out_size, void* d_ws, size_t ws_size,
                              hipStream_t stream) {
    const vf4* x = (const vf4*)d_in[0];
    vf4* out = (vf4*)d_out;
    vf4* sums = (vf4*)d_ws;                 // 4 MiB, fully written each launch
    unsigned int* cnt = (unsigned int*)((char*)d_ws + SUMS_BYTES);

    // barrier counter must start at 0 (ws is poisoned between iterations)
    hipMemsetAsync(cnt, 0, 64, stream);
    ds_fused<<<NBLK, 256, 0, stream>>>(x, sums, cnt, out);
}

// Round 3
// 214.359 us; speedup vs baseline: 1.7487x; 1.7487x over previous
//
#include <hip/hip_runtime.h>

// x: (B=8, L=8192, D=512) fp32.  out: (B, 2048, D) fp32.
// out[b,i,d] = (sum_{l<=4(i+1)-1} x[b,l,d]) / (4(i+1))
//
// Fused single-pass chunked scan, R8.
// R6/R7 post-mortem: the manual grid barrier used __threadfence() at agent
// scope, which on gfx95x emits buffer_wbl2 (full L2 writeback) on release
// and buffer_inv (full L2 invalidate) on acquire -- ONE PER BLOCK.  512-1024
// serialized L2 maintenance ops, and the invs kept wiping L2 *during* the
// phase-B prefix loop.  Symptom matched: time scaled with block count
// (R6 512 blk = 109us, R7 1024 blk = 221us) while VALUBusy=2% and BW=0.5TB/s.
//
// R8 removes ALL cache-maintenance ops:
//   * sums[] is accessed ONLY with device-scope (sc1) loads/stores via
//     inline asm -- they bypass the non-coherent per-XCD L2 and are served
//     at the Infinity-Cache coherence point.  No wbl2/inv needed, ever.
//   * barrier = vmcnt(0) drain (__syncthreads) + RELAXED agent atomicAdd +
//     RELAXED spin.  sc1 stores are already globally visible once retired.
//   * geometry identical to R6 (NC=128, 512 blocks, 2 blk/CU co-resident,
//     proven by R6/R7 passing) -> clean A/B on the coherence mechanism.

#define BB   8
#define LL   8192
#define DD4  128            // D / 4 (float4 granularity)
#define NC   128            // chunks along L
#define CL   (LL / NC)      // 64 rows per chunk
#define OPC  (CL / 4)       // 16 outputs per chunk per column
#define OL   (LL / 4)       // 2048 output rows
#define NBLK 512            // grid size; co-resident (2 blocks/CU, no LDS)
#define SUMS_BYTES ((size_t)BB * NC * DD4 * 16)   // 2 MiB of chunk totals

typedef float vf4 __attribute__((ext_vector_type(4)));

// device-scope (agent-coherent) 16B access: sc1 bypasses the per-XCD L2.
__device__ __forceinline__ void store_dev(vf4* p, vf4 v) {
    asm volatile("global_store_dwordx4 %0, %1, off sc1" :: "v"(p), "v"(v) : "memory");
}
__device__ __forceinline__ vf4 load_dev(const vf4* p) {
    vf4 r;
    asm volatile("global_load_dwordx4 %0, %1, off sc1" : "=v"(r) : "v"(p) : "memory");
    return r;
}
__device__ __forceinline__ void wait_vm0() {
    asm volatile("s_waitcnt vmcnt(0)" ::: "memory");
    __builtin_amdgcn_sched_barrier(0);   // rule #18: pin consumers after the wait
}

__global__ __launch_bounds__(256) void ds_fused(const vf4* __restrict__ x,
                                                vf4* __restrict__ sums,
                                                unsigned int* __restrict__ cnt,
                                                vf4* __restrict__ out) {
    const int tid = blockIdx.x * blockDim.x + threadIdx.x;
    const int d4 = tid & (DD4 - 1);
    const int c  = (tid >> 7) & (NC - 1);
    const int b  = tid >> 14;

    const vf4* p = x + (((size_t)b * LL + c * CL) * DD4 + d4);

    // ---- phase A: stream chunk, checkpoints -> registers/AGPRs ----
    vf4 v[OPC];                       // statically indexed
    vf4 s = (vf4)0.f;
    #pragma unroll
    for (int j = 0; j < CL; j += 8) {
        // 8 independent NT loads in flight before any use (x never re-read;
        // the 512MB poison fill flushes L3 between iterations anyway)
        vf4 v0 = __builtin_nontemporal_load(&p[(j + 0) * DD4]);
        vf4 v1 = __builtin_nontemporal_load(&p[(j + 1) * DD4]);
        vf4 v2 = __builtin_nontemporal_load(&p[(j + 2) * DD4]);
        vf4 v3 = __builtin_nontemporal_load(&p[(j + 3) * DD4]);
        vf4 v4 = __builtin_nontemporal_load(&p[(j + 4) * DD4]);
        vf4 v5 = __builtin_nontemporal_load(&p[(j + 5) * DD4]);
        vf4 v6 = __builtin_nontemporal_load(&p[(j + 6) * DD4]);
        vf4 v7 = __builtin_nontemporal_load(&p[(j + 7) * DD4]);
        s += v0 + v1 + v2 + v3;
        v[(j >> 2) + 0] = s;
        s += v4 + v5 + v6 + v7;
        v[(j >> 2) + 1] = s;
    }
    store_dev(sums + (b * NC + c) * DD4 + d4, s);   // chunk total @ coherent point

    // ---- manual grid barrier: NO cache-maintenance ops ----
    wait_vm0();                       // sc1 store retired => globally visible
    __syncthreads();
    if (threadIdx.x == 0) {
        __hip_atomic_fetch_add(cnt, 1u, __ATOMIC_RELAXED, __HIP_MEMORY_SCOPE_AGENT);
        while (__hip_atomic_load(cnt, __ATOMIC_RELAXED, __HIP_MEMORY_SCOPE_AGENT) < NBLK)
            __builtin_amdgcn_s_sleep(8);
    }
    __syncthreads();

    // ---- phase B: exclusive prefix over preceding chunk totals ----
    // sc1 loads (coherent, L3-served); 8 issued per batch before one wait.
    vf4 r0 = (vf4)0.f, r1 = (vf4)0.f, r2 = (vf4)0.f, r3 = (vf4)0.f;
    vf4 r4 = (vf4)0.f, r5 = (vf4)0.f, r6 = (vf4)0.f, r7 = (vf4)0.f;
    const vf4* sp = sums + b * NC * DD4 + d4;
    int q = 0;
    for (; q + 8 <= c; q += 8) {
        vf4 t0 = load_dev(sp + (q + 0) * DD4);
        vf4 t1 = load_dev(sp + (q + 1) * DD4);
        vf4 t2 = load_dev(sp + (q + 2) * DD4);
        vf4 t3 = load_dev(sp + (q + 3) * DD4);
        vf4 t4 = load_dev(sp + (q + 4) * DD4);
        vf4 t5 = load_dev(sp + (q + 5) * DD4);
        vf4 t6 = load_dev(sp + (q + 6) * DD4);
        vf4 t7 = load_dev(sp + (q + 7) * DD4);
        wait_vm0();
        r0 += t0; r1 += t1; r2 += t2; r3 += t3;
        r4 += t4; r5 += t5; r6 += t6; r7 += t7;
    }
    for (; q < c; ++q) {
        vf4 t = load_dev(sp + q * DD4);
        wait_vm0();
        r0 += t;
    }
    const vf4 r = ((r0 + r1) + (r2 + r3)) + ((r4 + r5) + (r6 + r7));

    // ---- phase C: scale registers, single final write ----
    vf4* o = out + (((size_t)b * OL + c * OPC) * DD4 + d4);
    const int base = c * CL;
    #pragma unroll
    for (int k = 0; k < OPC; ++k) {
        const float inv = 1.0f / (float)(base + 4 * k + 4);
        __builtin_nontemporal_store((v[k] + r) * inv, &o[(size_t)k * DD4]);
    }
}

extern "C" void kernel_launch(void* const* d_in, const int* in_sizes, int n_in,
                              void* d_out, int out_size, void* d_ws, size_t ws_size,
                              hipStream_t stream) {
    const vf4* x = (const vf4*)d_in[0];
    vf4* out = (vf4*)d_out;
    vf4* sums = (vf4*)d_ws;                 // 2 MiB, fully written each launch
    unsigned int* cnt = (unsigned int*)((char*)d_ws + SUMS_BYTES);

    // barrier counter must start at 0 (ws is poisoned between iterations);
    // inter-kernel coherence makes the memset visible to agent atomics.
    hipMemsetAsync(cnt, 0, 64, stream);
    ds_fused<<<NBLK, 256, 0, stream>>>(x, sums, cnt, out);
}

// Round 4
// 196.382 us; speedup vs baseline: 1.9087x; 1.0915x over previous
//
#include <hip/hip_runtime.h>

// x: (B=8, L=8192, D=512) fp32.  out: (B, 2048, D) fp32.
// out[b,i,d] = (sum_{l<=4(i+1)-1} x[b,l,d]) / (4(i+1))
//
// Fused single-pass chunked scan, R9.
// R8 (fence-free sc1 barrier) measured ~54us kernel (214 total - ~160us of
// captured harness poison fills).  Remaining slack over the ~30us roofline:
//   * phase B quadratic prefix: NC=128 -> 133 MB of sc1 L3 reads (~13us)
//   * 512-block barrier arrival skew
// R9: NC 128->64 (CL=128).  Phase-B traffic ~ NC^2 -> 33 MB (~4us); 256
// blocks (1/CU, co-resident trivially); phase A gets 16-deep NT load
// batches (2x in-flight bytes for the cold-HBM case).  Checkpoints = 32
// vf4 = 128 regs -> compiler parks them in AGPRs; unified file, ~240 regs
// total, no spill (R6/R8 proved AGPR-parked checkpoints stream fine; R7's
// AGPR diagnosis was wrong -- the fences were the problem).
// Coherence mechanism identical to R8 (validated): sums via sc1 loads/
// stores only, barrier = vmcnt(0) + relaxed agent atomics, ZERO cache-
// maintenance instructions.

#define BB   8
#define LL   8192
#define DD4  128            // D / 4 (float4 granularity)
#define NC   64             // chunks along L
#define CL   (LL / NC)      // 128 rows per chunk
#define OPC  (CL / 4)       // 32 outputs per chunk per column
#define OL   (LL / 4)       // 2048 output rows
#define NBLK 256            // grid size; 1 block/CU, co-resident trivially
#define SUMS_BYTES ((size_t)BB * NC * DD4 * 16)   // 1 MiB of chunk totals

typedef float vf4 __attribute__((ext_vector_type(4)));

// device-scope (agent-coherent) 16B access: sc1 bypasses the per-XCD L2.
__device__ __forceinline__ void store_dev(vf4* p, vf4 v) {
    asm volatile("global_store_dwordx4 %0, %1, off sc1" :: "v"(p), "v"(v) : "memory");
}
__device__ __forceinline__ vf4 load_dev(const vf4* p) {
    vf4 r;
    asm volatile("global_load_dwordx4 %0, %1, off sc1" : "=v"(r) : "v"(p) : "memory");
    return r;
}
__device__ __forceinline__ void wait_vm0() {
    asm volatile("s_waitcnt vmcnt(0)" ::: "memory");
    __builtin_amdgcn_sched_barrier(0);   // rule #18: pin consumers after the wait
}

__global__ __launch_bounds__(256) void ds_fused(const vf4* __restrict__ x,
                                                vf4* __restrict__ sums,
                                                unsigned int* __restrict__ cnt,
                                                vf4* __restrict__ out) {
    const int tid = blockIdx.x * blockDim.x + threadIdx.x;
    const int d4 = tid & (DD4 - 1);
    const int c  = (tid >> 7) & (NC - 1);
    const int b  = tid >> 13;

    const vf4* p = x + (((size_t)b * LL + c * CL) * DD4 + d4);

    // ---- phase A: stream 128-row chunk, 32 checkpoints -> regs/AGPRs ----
    vf4 v[OPC];                       // statically indexed throughout
    vf4 s = (vf4)0.f;
    #pragma unroll
    for (int j = 0; j < CL; j += 16) {
        // 16 independent NT loads in flight before any use (x never re-read;
        // poison fill flushes L3 between timed iterations anyway)
        vf4 v0  = __builtin_nontemporal_load(&p[(j +  0) * DD4]);
        vf4 v1  = __builtin_nontemporal_load(&p[(j +  1) * DD4]);
        vf4 v2  = __builtin_nontemporal_load(&p[(j +  2) * DD4]);
        vf4 v3  = __builtin_nontemporal_load(&p[(j +  3) * DD4]);
        vf4 v4  = __builtin_nontemporal_load(&p[(j +  4) * DD4]);
        vf4 v5  = __builtin_nontemporal_load(&p[(j +  5) * DD4]);
        vf4 v6  = __builtin_nontemporal_load(&p[(j +  6) * DD4]);
        vf4 v7  = __builtin_nontemporal_load(&p[(j +  7) * DD4]);
        vf4 v8  = __builtin_nontemporal_load(&p[(j +  8) * DD4]);
        vf4 v9  = __builtin_nontemporal_load(&p[(j +  9) * DD4]);
        vf4 v10 = __builtin_nontemporal_load(&p[(j + 10) * DD4]);
        vf4 v11 = __builtin_nontemporal_load(&p[(j + 11) * DD4]);
        vf4 v12 = __builtin_nontemporal_load(&p[(j + 12) * DD4]);
        vf4 v13 = __builtin_nontemporal_load(&p[(j + 13) * DD4]);
        vf4 v14 = __builtin_nontemporal_load(&p[(j + 14) * DD4]);
        vf4 v15 = __builtin_nontemporal_load(&p[(j + 15) * DD4]);
        s += v0 + v1 + v2 + v3;
        v[(j >> 2) + 0] = s;
        s += v4 + v5 + v6 + v7;
        v[(j >> 2) + 1] = s;
        s += v8 + v9 + v10 + v11;
        v[(j >> 2) + 2] = s;
        s += v12 + v13 + v14 + v15;
        v[(j >> 2) + 3] = s;
    }
    store_dev(sums + (b * NC + c) * DD4 + d4, s);   // chunk total @ coherent point

    // ---- manual grid barrier: NO cache-maintenance ops (R8 mechanism) ----
    wait_vm0();                       // sc1 store retired => globally visible
    __syncthreads();
    if (threadIdx.x == 0) {
        __hip_atomic_fetch_add(cnt, 1u, __ATOMIC_RELAXED, __HIP_MEMORY_SCOPE_AGENT);
        while (__hip_atomic_load(cnt, __ATOMIC_RELAXED, __HIP_MEMORY_SCOPE_AGENT) < NBLK)
            __builtin_amdgcn_s_sleep(8);
    }
    __syncthreads();

    // ---- phase B: exclusive prefix over preceding chunk totals ----
    // sc1 loads (coherent, L3-served); avg 32 per thread, 33 MB aggregate.
    vf4 r0 = (vf4)0.f, r1 = (vf4)0.f, r2 = (vf4)0.f, r3 = (vf4)0.f;
    vf4 r4 = (vf4)0.f, r5 = (vf4)0.f, r6 = (vf4)0.f, r7 = (vf4)0.f;
    const vf4* sp = sums + b * NC * DD4 + d4;
    int q = 0;
    for (; q + 8 <= c; q += 8) {
        vf4 t0 = load_dev(sp + (q + 0) * DD4);
        vf4 t1 = load_dev(sp + (q + 1) * DD4);
        vf4 t2 = load_dev(sp + (q + 2) * DD4);
        vf4 t3 = load_dev(sp + (q + 3) * DD4);
        vf4 t4 = load_dev(sp + (q + 4) * DD4);
        vf4 t5 = load_dev(sp + (q + 5) * DD4);
        vf4 t6 = load_dev(sp + (q + 6) * DD4);
        vf4 t7 = load_dev(sp + (q + 7) * DD4);
        wait_vm0();
        r0 += t0; r1 += t1; r2 += t2; r3 += t3;
        r4 += t4; r5 += t5; r6 += t6; r7 += t7;
    }
    for (; q < c; ++q) {
        vf4 t = load_dev(sp + q * DD4);
        wait_vm0();
        r0 += t;
    }
    const vf4 r = ((r0 + r1) + (r2 + r3)) + ((r4 + r5) + (r6 + r7));

    // ---- phase C: scale registers, single final write ----
    vf4* o = out + (((size_t)b * OL + c * OPC) * DD4 + d4);
    const int base = c * CL;
    #pragma unroll
    for (int k = 0; k < OPC; ++k) {
        const float inv = 1.0f / (float)(base + 4 * k + 4);
        __builtin_nontemporal_store((v[k] + r) * inv, &o[(size_t)k * DD4]);
    }
}

extern "C" void kernel_launch(void* const* d_in, const int* in_sizes, int n_in,
                              void* d_out, int out_size, void* d_ws, size_t ws_size,
                              hipStream_t stream) {
    const vf4* x = (const vf4*)d_in[0];
    vf4* out = (vf4*)d_out;
    vf4* sums = (vf4*)d_ws;                 // 1 MiB, fully written each launch
    unsigned int* cnt = (unsigned int*)((char*)d_ws + SUMS_BYTES);

    // barrier counter must start at 0 (ws is poisoned between iterations)
    hipMemsetAsync(cnt, 0, 64, stream);
    ds_fused<<<NBLK, 256, 0, stream>>>(x, sums, cnt, out);
}